// Round 1
// baseline (338.851 us; speedup 1.0000x reference)
//
#include <hip/hip_runtime.h>
#include <hip/hip_bf16.h>

#define N_TOKENS 16384
#define DIM      2048
#define NEXP     64
#define TOPK     8
#define LOSCALE  2048.0f      // 2^11, exact power of two
#define NBLOCKS  512          // 32 tokens per block
#define NWAVES   8            // waves per block, K-split
#define KSLAB    256          // K per wave
#define NCHUNK   8            // KSLAB / 32
#define LSTRIDE  66           // LDS token stride: (264*quad+row16)%32 -> <=2-way
#define NREP     32           // replicated aux accumulators (16-way contention)

typedef _Float16 half8   __attribute__((ext_vector_type(8)));
typedef float    floatx4 __attribute__((ext_vector_type(4)));

// ---------------------------------------------------------------------------
// Kernel 0: split W (64x2048 fp32) into f16 hi/lo planes.
//   whi = (f16)w;  wlo = (f16)((w - (f32)whi) * 2^11)
// ---------------------------------------------------------------------------
__global__ __launch_bounds__(256) void wprep_kernel(const float* __restrict__ W,
                                                    _Float16* __restrict__ Whi,
                                                    _Float16* __restrict__ Wlo) {
    int i = blockIdx.x * 256 + threadIdx.x;           // grid 512 -> 131072
    float w = W[i];
    _Float16 h = (_Float16)w;
    Whi[i] = h;
    Wlo[i] = (_Float16)((w - (float)h) * LOSCALE);
}

// ---------------------------------------------------------------------------
// Fused kernel: MFMA router GEMM + softmax + top-8 + aux partials + (last
// block) aux finalize. Logits never touch HBM.
//   - 512 blocks x 8 waves; block owns 32 tokens; waves K-split (256 k each).
//     16 waves/CU (4/SIMD) vs previous 8/CU -- kernel was latency-bound at
//     OccupancyPercent=20 with nothing busy (Mfma 4%, VALU 18%, HBM 8%).
//   - K-loop: f16-split MFMA (a ~ ah + al/2^11; dropped ll term ~2^-22|a||b|,
//     validated index-exact in prior session). No LDS, no barriers in loop;
//     next chunk's loads issued before current MFMAs.
//   - Exchange: partial logits -> LDS [wave][tok][exp], token stride 66
//     (writes/reads <=2-way bank aliasing = free). One barrier.
//   - Epilogue: wave w does softmax + rank-select for tokens [4w,4w+4);
//     rank_i = #{j: s_j>s_i or (s_j==s_i and j<i)} = lax.top_k semantics.
//   - aux: per-lane cnt/sp -> LDS reduce -> global atomics into replica
//     blockIdx&31 (kills the 512-way same-address storm); last block
//     (ticket) sums replicas via atomic reads and writes aux_loss.
// ---------------------------------------------------------------------------
__global__ __launch_bounds__(512, 4) void moe_kernel(const float* __restrict__ A,
                                                     const _Float16* __restrict__ Whi,
                                                     const _Float16* __restrict__ Wlo,
                                                     float* __restrict__ out_w,
                                                     float* __restrict__ out_i,
                                                     float* __restrict__ out_aux,
                                                     float* __restrict__ cnt_ws,
                                                     float* __restrict__ sp_ws,
                                                     unsigned int* __restrict__ ticket) {
    __shared__ float lds[NWAVES * 32 * LSTRIDE];   // 67.6 KB
    __shared__ float s_cnt[NEXP];
    __shared__ float s_sp[NEXP];
    __shared__ int   s_last;

    const int lane  = threadIdx.x & 63;
    const int wv    = threadIdx.x >> 6;      // k-slab 0..7
    const int row16 = lane & 15;
    const int quad  = lane >> 4;
    const int tbase = blockIdx.x * 32;
    const int kbase = wv * KSLAB;

    if (threadIdx.x < NEXP) { s_cnt[threadIdx.x] = 0.f; s_sp[threadIdx.x] = 0.f; }

    floatx4 acc0[2][4] = {};   // hi*hi
    floatx4 acc1[2][4] = {};   // hi*lo_s + lo_s*hi (carries 2^11)

    const float* ap0 = A + (size_t)(tbase + row16) * DIM + quad * 8;
    const float* ap1 = ap0 + (size_t)16 * DIM;
    const size_t boff = (size_t)row16 * DIM + quad * 8;

    // prologue loads (chunk 0)
    float4 ar[2][2];
    half8  bh[4], bl[4];
    ar[0][0] = *(const float4*)(ap0 + kbase);
    ar[0][1] = *(const float4*)(ap0 + kbase + 4);
    ar[1][0] = *(const float4*)(ap1 + kbase);
    ar[1][1] = *(const float4*)(ap1 + kbase + 4);
    #pragma unroll
    for (int nt = 0; nt < 4; ++nt) {
        bh[nt] = *(const half8*)(Whi + (size_t)nt * 16 * DIM + boff + kbase);
        bl[nt] = *(const half8*)(Wlo + (size_t)nt * 16 * DIM + boff + kbase);
    }

    for (int it = 0; it < NCHUNK; ++it) {
        // issue next chunk's loads first; they fly during split + MFMA
        float4 arn[2][2];
        half8  bhn[4], bln[4];
        if (it < NCHUNK - 1) {
            int kc = kbase + (it + 1) * 32;
            arn[0][0] = *(const float4*)(ap0 + kc);
            arn[0][1] = *(const float4*)(ap0 + kc + 4);
            arn[1][0] = *(const float4*)(ap1 + kc);
            arn[1][1] = *(const float4*)(ap1 + kc + 4);
            #pragma unroll
            for (int nt = 0; nt < 4; ++nt) {
                bhn[nt] = *(const half8*)(Whi + (size_t)nt * 16 * DIM + boff + kc);
                bln[nt] = *(const half8*)(Wlo + (size_t)nt * 16 * DIM + boff + kc);
            }
        }

        // split current A f32 -> f16 hi/lo
        half8 ah[2], al[2];
        #pragma unroll
        for (int mt = 0; mt < 2; ++mt) {
            float av[8] = {ar[mt][0].x, ar[mt][0].y, ar[mt][0].z, ar[mt][0].w,
                           ar[mt][1].x, ar[mt][1].y, ar[mt][1].z, ar[mt][1].w};
            #pragma unroll
            for (int j = 0; j < 8; ++j) {
                _Float16 h = (_Float16)av[j];
                ah[mt][j] = h;
                al[mt][j] = (_Float16)((av[j] - (float)h) * LOSCALE);
            }
        }

        #pragma unroll
        for (int mt = 0; mt < 2; ++mt)
            #pragma unroll
            for (int nt = 0; nt < 4; ++nt) {
                acc0[mt][nt] = __builtin_amdgcn_mfma_f32_16x16x32_f16(ah[mt], bh[nt], acc0[mt][nt], 0, 0, 0);
                acc1[mt][nt] = __builtin_amdgcn_mfma_f32_16x16x32_f16(ah[mt], bl[nt], acc1[mt][nt], 0, 0, 0);
                acc1[mt][nt] = __builtin_amdgcn_mfma_f32_16x16x32_f16(al[mt], bh[nt], acc1[mt][nt], 0, 0, 0);
            }

        #pragma unroll
        for (int mt = 0; mt < 2; ++mt) { ar[mt][0] = arn[mt][0]; ar[mt][1] = arn[mt][1]; }
        #pragma unroll
        for (int nt = 0; nt < 4; ++nt) { bh[nt] = bhn[nt]; bl[nt] = bln[nt]; }
    }

    // partial logits -> LDS ; C layout: col=lane&15 (expert), row=quad*4+reg
    const float inv = 1.0f / LOSCALE;
    #pragma unroll
    for (int mt = 0; mt < 2; ++mt)
        #pragma unroll
        for (int nt = 0; nt < 4; ++nt)
            #pragma unroll
            for (int reg = 0; reg < 4; ++reg) {
                int tok = mt * 16 + quad * 4 + reg;
                lds[(wv * 32 + tok) * LSTRIDE + nt * 16 + row16] =
                    acc0[mt][nt][reg] + acc1[mt][nt][reg] * inv;
            }
    __syncthreads();

    // epilogue: wave wv handles tokens [wv*4, wv*4+4); lane = expert
    float sp = 0.f, cnt = 0.f;
    for (int i = 0; i < 4; ++i) {
        int t = wv * 4 + i;
        float lg01 = lds[t * LSTRIDE + lane]         + lds[(32 + t) * LSTRIDE + lane];
        float lg23 = lds[(64 + t) * LSTRIDE + lane]  + lds[(96 + t) * LSTRIDE + lane];
        float lg45 = lds[(128 + t) * LSTRIDE + lane] + lds[(160 + t) * LSTRIDE + lane];
        float lg67 = lds[(192 + t) * LSTRIDE + lane] + lds[(224 + t) * LSTRIDE + lane];
        float lg = (lg01 + lg23) + (lg45 + lg67);

        float m = lg;
        #pragma unroll
        for (int off = 32; off; off >>= 1) m = fmaxf(m, __shfl_xor(m, off));
        float e = expf(lg - m);
        float ssum = e;
        #pragma unroll
        for (int off = 32; off; off >>= 1) ssum += __shfl_xor(ssum, off);
        float score = e / ssum;
        sp += score;

        int rank = 0;
        #pragma unroll
        for (int j = 0; j < 64; ++j) {
            float sj = __shfl(score, j);
            rank += (sj > score) || (sj == score && j < lane);
        }
        bool sel = rank < TOPK;

        float v = sel ? score : 0.f;
        #pragma unroll
        for (int off = 32; off; off >>= 1) v += __shfl_xor(v, off);

        if (sel) {
            out_w[(size_t)(tbase + t) * TOPK + rank] = score / v;
            out_i[(size_t)(tbase + t) * TOPK + rank] = (float)lane;
            cnt += 1.f;
        }
    }

    atomicAdd(&s_sp[lane], sp);
    atomicAdd(&s_cnt[lane], cnt);
    __syncthreads();
    const int rep = (blockIdx.x & (NREP - 1)) * NEXP;
    if (threadIdx.x < 64)       atomicAdd(&cnt_ws[rep + threadIdx.x], s_cnt[threadIdx.x]);
    else if (threadIdx.x < 128) atomicAdd(&sp_ws[rep + threadIdx.x - 64], s_sp[threadIdx.x - 64]);

    // release our atomics, then take a ticket; last block finalizes
    __threadfence();
    __syncthreads();
    if (threadIdx.x == 0)
        s_last = (atomicAdd(ticket, 1u) == (unsigned)(gridDim.x - 1));
    __syncthreads();
    if (s_last && threadIdx.x < 64) {
        float c = 0.f, p = 0.f;
        #pragma unroll
        for (int r = 0; r < NREP; ++r) {
            c += atomicAdd(&cnt_ws[r * NEXP + threadIdx.x], 0.f);   // device-scope read
            p += atomicAdd(&sp_ws [r * NEXP + threadIdx.x], 0.f);
        }
        float v = (c / (float)(N_TOKENS * TOPK)) * (p / (float)N_TOKENS);
        #pragma unroll
        for (int off = 32; off; off >>= 1) v += __shfl_xor(v, off);
        if (threadIdx.x == 0) out_aux[0] = 0.001f * (float)NEXP * v;
    }
}

extern "C" void kernel_launch(void* const* d_in, const int* in_sizes, int n_in,
                              void* d_out, int out_size, void* d_ws, size_t ws_size,
                              hipStream_t stream) {
    const float* A = (const float*)d_in[0];   // hidden_states (16384 x 2048)
    const float* W = (const float*)d_in[1];   // weight        (64 x 2048)
    float* out = (float*)d_out;

    _Float16*     whi    = (_Float16*)d_ws;
    _Float16*     wlo    = whi + (size_t)NEXP * DIM;
    float*        cnt_ws = (float*)(wlo + (size_t)NEXP * DIM);
    float*        sp_ws  = cnt_ws + (size_t)NREP * NEXP;
    unsigned int* ticket = (unsigned int*)(sp_ws + (size_t)NREP * NEXP);

    // zero cnt(8KB) + sp(8KB) + ticket(4B)
    hipMemsetAsync(cnt_ws, 0, 2 * NREP * NEXP * sizeof(float) + sizeof(unsigned int), stream);

    hipLaunchKernelGGL(wprep_kernel, dim3(NEXP * DIM / 256), dim3(256), 0, stream,
                       W, whi, wlo);

    float* out_w = out;
    float* out_i = out + (size_t)N_TOKENS * TOPK;
    float* out_a = out + 2 * (size_t)N_TOKENS * TOPK;

    hipLaunchKernelGGL(moe_kernel, dim3(NBLOCKS), dim3(512), 0, stream,
                       A, whi, wlo, out_w, out_i, out_a, cnt_ws, sp_ws, ticket);
}

// Round 2
// 304.907 us; speedup vs baseline: 1.1113x; 1.1113x over previous
//
#include <hip/hip_runtime.h>
#include <hip/hip_bf16.h>

#define N_TOKENS 16384
#define DIM      2048
#define NEXP     64
#define TOPK     8
#define LOSCALE  2048.0f      // 2^11, exact power of two
#define NBLOCKS  512          // 32 tokens per block
#define NWAVES   8            // waves per block, K-split
#define KSLAB    256          // K per wave
#define NCHUNK   8            // KSLAB / 32
#define LSTRIDE  66           // LDS token stride: (264*quad+row16)%32 -> <=2-way
#define NREP     32           // replicated aux accumulators (16-way contention)

typedef _Float16 half8   __attribute__((ext_vector_type(8)));
typedef float    floatx4 __attribute__((ext_vector_type(4)));

// ---------------------------------------------------------------------------
// Kernel 0: split W (64x2048 fp32) into f16 hi/lo planes.
//   whi = (f16)w;  wlo = (f16)((w - (f32)whi) * 2^11)
// ---------------------------------------------------------------------------
__global__ __launch_bounds__(256) void wprep_kernel(const float* __restrict__ W,
                                                    _Float16* __restrict__ Whi,
                                                    _Float16* __restrict__ Wlo) {
    int i = blockIdx.x * 256 + threadIdx.x;           // grid 512 -> 131072
    float w = W[i];
    _Float16 h = (_Float16)w;
    Whi[i] = h;
    Wlo[i] = (_Float16)((w - (float)h) * LOSCALE);
}

// ---------------------------------------------------------------------------
// Fused kernel: MFMA router GEMM + softmax + top-8 + aux partials + (last
// block) aux finalize. Logits never touch HBM.
//   - 512 blocks x 8 waves; block owns 32 tokens; waves K-split (256 k each).
//     16 waves/CU (4/SIMD). __launch_bounds__(512, 2): measured on this
//     toolchain arg2 acts as min-BLOCKS/CU (R1: arg2=4 -> 64-VGPR cap ->
//     95 MB scratch spills, dur 199us). 2 blocks/CU -> 128-VGPR cap, which
//     fits the ~116-VGPR pipelined body with zero spill, and matches the
//     LDS-limited 2 blocks/CU (2 x 68.6 KB <= 160 KB).
//   - K-loop: f16-split MFMA (a ~ ah + al/2^11; dropped ll term ~2^-22|a||b|,
//     validated index-exact previously). No LDS/barriers in loop; next
//     chunk's loads issued before current MFMAs.
//   - Exchange: partial logits -> LDS [wave][tok][exp], token stride 66
//     (writes/reads <=2-way bank aliasing = free). One barrier.
//   - Epilogue: wave w does softmax + rank-select for tokens [4w,4w+4);
//     rank_i = #{j: s_j>s_i or (s_j==s_i and j<i)} = lax.top_k semantics.
//   - aux: per-lane cnt/sp -> LDS reduce -> global atomics into replica
//     blockIdx&31 (16-way contention max); last block (ticket) sums the
//     replicas via device-scope atomic reads and writes aux_loss.
// ---------------------------------------------------------------------------
__global__ __launch_bounds__(512, 2) void moe_kernel(const float* __restrict__ A,
                                                     const _Float16* __restrict__ Whi,
                                                     const _Float16* __restrict__ Wlo,
                                                     float* __restrict__ out_w,
                                                     float* __restrict__ out_i,
                                                     float* __restrict__ out_aux,
                                                     float* __restrict__ cnt_ws,
                                                     float* __restrict__ sp_ws,
                                                     unsigned int* __restrict__ ticket) {
    __shared__ float lds[NWAVES * 32 * LSTRIDE];   // 67.6 KB
    __shared__ float s_cnt[NEXP];
    __shared__ float s_sp[NEXP];
    __shared__ int   s_last;

    const int lane  = threadIdx.x & 63;
    const int wv    = threadIdx.x >> 6;      // k-slab 0..7
    const int row16 = lane & 15;
    const int quad  = lane >> 4;
    const int tbase = blockIdx.x * 32;
    const int kbase = wv * KSLAB;

    if (threadIdx.x < NEXP) { s_cnt[threadIdx.x] = 0.f; s_sp[threadIdx.x] = 0.f; }

    floatx4 acc0[2][4] = {};   // hi*hi
    floatx4 acc1[2][4] = {};   // hi*lo_s + lo_s*hi (carries 2^11)

    const float* ap0 = A + (size_t)(tbase + row16) * DIM + quad * 8;
    const float* ap1 = ap0 + (size_t)16 * DIM;
    const size_t boff = (size_t)row16 * DIM + quad * 8;

    // prologue loads (chunk 0)
    float4 ar[2][2];
    half8  bh[4], bl[4];
    ar[0][0] = *(const float4*)(ap0 + kbase);
    ar[0][1] = *(const float4*)(ap0 + kbase + 4);
    ar[1][0] = *(const float4*)(ap1 + kbase);
    ar[1][1] = *(const float4*)(ap1 + kbase + 4);
    #pragma unroll
    for (int nt = 0; nt < 4; ++nt) {
        bh[nt] = *(const half8*)(Whi + (size_t)nt * 16 * DIM + boff + kbase);
        bl[nt] = *(const half8*)(Wlo + (size_t)nt * 16 * DIM + boff + kbase);
    }

    for (int it = 0; it < NCHUNK; ++it) {
        // issue next chunk's loads first; they fly during split + MFMA
        float4 arn[2][2];
        half8  bhn[4], bln[4];
        if (it < NCHUNK - 1) {
            int kc = kbase + (it + 1) * 32;
            arn[0][0] = *(const float4*)(ap0 + kc);
            arn[0][1] = *(const float4*)(ap0 + kc + 4);
            arn[1][0] = *(const float4*)(ap1 + kc);
            arn[1][1] = *(const float4*)(ap1 + kc + 4);
            #pragma unroll
            for (int nt = 0; nt < 4; ++nt) {
                bhn[nt] = *(const half8*)(Whi + (size_t)nt * 16 * DIM + boff + kc);
                bln[nt] = *(const half8*)(Wlo + (size_t)nt * 16 * DIM + boff + kc);
            }
        }

        // split current A f32 -> f16 hi/lo
        half8 ah[2], al[2];
        #pragma unroll
        for (int mt = 0; mt < 2; ++mt) {
            float av[8] = {ar[mt][0].x, ar[mt][0].y, ar[mt][0].z, ar[mt][0].w,
                           ar[mt][1].x, ar[mt][1].y, ar[mt][1].z, ar[mt][1].w};
            #pragma unroll
            for (int j = 0; j < 8; ++j) {
                _Float16 h = (_Float16)av[j];
                ah[mt][j] = h;
                al[mt][j] = (_Float16)((av[j] - (float)h) * LOSCALE);
            }
        }

        #pragma unroll
        for (int mt = 0; mt < 2; ++mt)
            #pragma unroll
            for (int nt = 0; nt < 4; ++nt) {
                acc0[mt][nt] = __builtin_amdgcn_mfma_f32_16x16x32_f16(ah[mt], bh[nt], acc0[mt][nt], 0, 0, 0);
                acc1[mt][nt] = __builtin_amdgcn_mfma_f32_16x16x32_f16(ah[mt], bl[nt], acc1[mt][nt], 0, 0, 0);
                acc1[mt][nt] = __builtin_amdgcn_mfma_f32_16x16x32_f16(al[mt], bh[nt], acc1[mt][nt], 0, 0, 0);
            }

        #pragma unroll
        for (int mt = 0; mt < 2; ++mt) { ar[mt][0] = arn[mt][0]; ar[mt][1] = arn[mt][1]; }
        #pragma unroll
        for (int nt = 0; nt < 4; ++nt) { bh[nt] = bhn[nt]; bl[nt] = bln[nt]; }
    }

    // partial logits -> LDS ; C layout: col=lane&15 (expert), row=quad*4+reg
    const float inv = 1.0f / LOSCALE;
    #pragma unroll
    for (int mt = 0; mt < 2; ++mt)
        #pragma unroll
        for (int nt = 0; nt < 4; ++nt)
            #pragma unroll
            for (int reg = 0; reg < 4; ++reg) {
                int tok = mt * 16 + quad * 4 + reg;
                lds[(wv * 32 + tok) * LSTRIDE + nt * 16 + row16] =
                    acc0[mt][nt][reg] + acc1[mt][nt][reg] * inv;
            }
    __syncthreads();

    // epilogue: wave wv handles tokens [wv*4, wv*4+4); lane = expert
    float sp = 0.f, cnt = 0.f;
    for (int i = 0; i < 4; ++i) {
        int t = wv * 4 + i;
        float lg01 = lds[t * LSTRIDE + lane]         + lds[(32 + t) * LSTRIDE + lane];
        float lg23 = lds[(64 + t) * LSTRIDE + lane]  + lds[(96 + t) * LSTRIDE + lane];
        float lg45 = lds[(128 + t) * LSTRIDE + lane] + lds[(160 + t) * LSTRIDE + lane];
        float lg67 = lds[(192 + t) * LSTRIDE + lane] + lds[(224 + t) * LSTRIDE + lane];
        float lg = (lg01 + lg23) + (lg45 + lg67);

        float m = lg;
        #pragma unroll
        for (int off = 32; off; off >>= 1) m = fmaxf(m, __shfl_xor(m, off));
        float e = expf(lg - m);
        float ssum = e;
        #pragma unroll
        for (int off = 32; off; off >>= 1) ssum += __shfl_xor(ssum, off);
        float score = e / ssum;
        sp += score;

        int rank = 0;
        #pragma unroll
        for (int j = 0; j < 64; ++j) {
            float sj = __shfl(score, j);
            rank += (sj > score) || (sj == score && j < lane);
        }
        bool sel = rank < TOPK;

        float v = sel ? score : 0.f;
        #pragma unroll
        for (int off = 32; off; off >>= 1) v += __shfl_xor(v, off);

        if (sel) {
            out_w[(size_t)(tbase + t) * TOPK + rank] = score / v;
            out_i[(size_t)(tbase + t) * TOPK + rank] = (float)lane;
            cnt += 1.f;
        }
    }

    atomicAdd(&s_sp[lane], sp);
    atomicAdd(&s_cnt[lane], cnt);
    __syncthreads();
    const int rep = (blockIdx.x & (NREP - 1)) * NEXP;
    if (threadIdx.x < 64)       atomicAdd(&cnt_ws[rep + threadIdx.x], s_cnt[threadIdx.x]);
    else if (threadIdx.x < 128) atomicAdd(&sp_ws[rep + threadIdx.x - 64], s_sp[threadIdx.x - 64]);

    // release our atomics, then take a ticket; last block finalizes
    __threadfence();
    __syncthreads();
    if (threadIdx.x == 0)
        s_last = (atomicAdd(ticket, 1u) == (unsigned)(gridDim.x - 1));
    __syncthreads();
    if (s_last && threadIdx.x < 64) {
        float c = 0.f, p = 0.f;
        #pragma unroll
        for (int r = 0; r < NREP; ++r) {
            c += atomicAdd(&cnt_ws[r * NEXP + threadIdx.x], 0.f);   // device-scope read
            p += atomicAdd(&sp_ws [r * NEXP + threadIdx.x], 0.f);
        }
        float v = (c / (float)(N_TOKENS * TOPK)) * (p / (float)N_TOKENS);
        #pragma unroll
        for (int off = 32; off; off >>= 1) v += __shfl_xor(v, off);
        if (threadIdx.x == 0) out_aux[0] = 0.001f * (float)NEXP * v;
    }
}

extern "C" void kernel_launch(void* const* d_in, const int* in_sizes, int n_in,
                              void* d_out, int out_size, void* d_ws, size_t ws_size,
                              hipStream_t stream) {
    const float* A = (const float*)d_in[0];   // hidden_states (16384 x 2048)
    const float* W = (const float*)d_in[1];   // weight        (64 x 2048)
    float* out = (float*)d_out;

    _Float16*     whi    = (_Float16*)d_ws;
    _Float16*     wlo    = whi + (size_t)NEXP * DIM;
    float*        cnt_ws = (float*)(wlo + (size_t)NEXP * DIM);
    float*        sp_ws  = cnt_ws + (size_t)NREP * NEXP;
    unsigned int* ticket = (unsigned int*)(sp_ws + (size_t)NREP * NEXP);

    // zero cnt(8KB) + sp(8KB) + ticket(4B)
    hipMemsetAsync(cnt_ws, 0, 2 * NREP * NEXP * sizeof(float) + sizeof(unsigned int), stream);

    hipLaunchKernelGGL(wprep_kernel, dim3(NEXP * DIM / 256), dim3(256), 0, stream,
                       W, whi, wlo);

    float* out_w = out;
    float* out_i = out + (size_t)N_TOKENS * TOPK;
    float* out_a = out + 2 * (size_t)N_TOKENS * TOPK;

    hipLaunchKernelGGL(moe_kernel, dim3(NBLOCKS), dim3(512), 0, stream,
                       A, whi, wlo, out_w, out_i, out_a, cnt_ws, sp_ws, ticket);
}